// Round 1
// baseline (103.978 us; speedup 1.0000x reference)
//
#include <hip/hip_runtime.h>

#define BATCH   512
#define EMBED   512
#define NF4     (EMBED / 4)     // float4s per row = 128
#define THREADS 512
#define GANCH   2               // anchors per block -> 256 blocks, 1 per CU

// Fully fused: per block, compute Gram rows for 2 anchors (GEMV from L2-resident X),
// then the hinge reduction for those anchors. No workspace use at all.
__global__ __launch_bounds__(THREADS) void fused_loss(
    const float* __restrict__ X,
    const int*   __restrict__ labels,
    const float* __restrict__ mu,
    const float* __restrict__ nv,
    float*       __restrict__ out,
    int n_classes)
{
    __shared__ float d0[BATCH];          // D[i0, :]
    __shared__ float d1[BATCH];          // D[i1, :]
    __shared__ float dijmu0[BATCH];      // D[i0, j] + mu_i0 for positives j
    __shared__ float dijmu1[BATCH];
    __shared__ int   lab[BATCH];
    __shared__ int   npos0_s, npos1_s;
    __shared__ float red[THREADS / 64];

    const int tid  = threadIdx.x;
    const int lane = tid & 63;
    const int wave = tid >> 6;
    const int sub  = lane & 7;           // lane within 8-lane row group
    const int rg   = lane >> 3;          // row group within wave
    const int i0   = blockIdx.x * GANCH;
    const int i1   = i0 + 1;

    lab[tid] = labels[tid];
    if (tid == 0) { npos0_s = 0; npos1_s = 0; }

    const float4* __restrict__ X4 = (const float4*)X;
    const float4* __restrict__ A0 = X4 + (size_t)i0 * NF4;
    const float4* __restrict__ A1 = X4 + (size_t)i1 * NF4;

    // Hoist both anchor vectors into registers: 16 float4 each per lane
    // (lane `sub` owns row elements f = c*8 + sub). 128 VGPRs, static indexing.
    float4 a0[16], a1[16];
#pragma unroll
    for (int c = 0; c < 16; ++c) {
        a0[c] = A0[c * 8 + sub];
        a1[c] = A1[c * 8 + sub];
    }

    // Phase 1: each wave covers 64 rows (8 passes x 8 row-groups).
    // 8 lanes cooperate per row; global loads are 8x128B segments per instr.
#pragma unroll 1
    for (int pass = 0; pass < 8; ++pass) {
        const int r = (wave << 6) + (pass << 3) + rg;
        const float4* __restrict__ Xr = X4 + (size_t)r * NF4;
        float acc0 = 0.f, acc1 = 0.f;
#pragma unroll
        for (int c = 0; c < 16; ++c) {
            const float4 x = Xr[c * 8 + sub];
            acc0 = fmaf(x.x, a0[c].x, acc0);
            acc0 = fmaf(x.y, a0[c].y, acc0);
            acc0 = fmaf(x.z, a0[c].z, acc0);
            acc0 = fmaf(x.w, a0[c].w, acc0);
            acc1 = fmaf(x.x, a1[c].x, acc1);
            acc1 = fmaf(x.y, a1[c].y, acc1);
            acc1 = fmaf(x.z, a1[c].z, acc1);
            acc1 = fmaf(x.w, a1[c].w, acc1);
        }
        // reduce across the 8 lanes of the row group (xor stays within group)
#pragma unroll
        for (int off = 1; off <= 4; off <<= 1) {
            acc0 += __shfl_xor(acc0, off, 64);
            acc1 += __shfl_xor(acc1, off, 64);
        }
        if (sub == 0) { d0[r] = acc0; d1[r] = acc1; }
    }

    __syncthreads();

    // Phase 2: hinge for both anchors.
    const int   l0  = lab[i0];
    const int   l1  = lab[i1];
    const float mu0 = mu[l0];
    const float mu1 = mu[l1];

    // compact positives (npos ~ 4 per anchor; shared-atomic order is fine)
    if (tid != i0 && lab[tid] == l0) {
        int p = atomicAdd(&npos0_s, 1);
        dijmu0[p] = d0[tid] + mu0;
    }
    if (tid != i1 && lab[tid] == l1) {
        int p = atomicAdd(&npos1_s, 1);
        dijmu1[p] = d1[tid] + mu1;
    }
    __syncthreads();

    const int npos0 = npos0_s;
    const int npos1 = npos1_s;

    float local = 0.f;
    const float dk0 = d0[tid];
    const float dk1 = d1[tid];
    if (lab[tid] != l0)
        for (int p = 0; p < npos0; ++p)
            local += fmaxf(dijmu0[p] - dk0, 0.f);
    if (lab[tid] != l1)
        for (int p = 0; p < npos1; ++p)
            local += fmaxf(dijmu1[p] - dk1, 0.f);

    // margin regularizers folded by block 0
    if (blockIdx.x == 0 && tid < n_classes)
        local -= (mu[tid] + nv[tid]) / (float)n_classes;

    // block reduction: wave shuffle -> LDS -> single atomic per block (256 total)
#pragma unroll
    for (int off = 32; off > 0; off >>= 1)
        local += __shfl_down(local, off, 64);
    if (lane == 0) red[wave] = local;
    __syncthreads();
    if (tid == 0) {
        float s = 0.f;
#pragma unroll
        for (int w = 0; w < THREADS / 64; ++w) s += red[w];
        atomicAdd(out, s);
    }
}

extern "C" void kernel_launch(void* const* d_in, const int* in_sizes, int n_in,
                              void* d_out, int out_size, void* d_ws, size_t ws_size,
                              hipStream_t stream)
{
    const float* X      = (const float*)d_in[0];
    const int*   labels = (const int*)d_in[1];
    const float* mu     = (const float*)d_in[2];
    const float* nv     = (const float*)d_in[3];
    float* out = (float*)d_out;
    const int n_classes = in_sizes[2];

    // out must start at 0 for the per-block atomics (memset node is graph-capturable)
    hipMemsetAsync(d_out, 0, sizeof(float), stream);

    fused_loss<<<dim3(BATCH / GANCH), dim3(THREADS), 0, stream>>>(
        X, labels, mu, nv, out, n_classes);
}

// Round 3
// 79.053 us; speedup vs baseline: 1.3153x; 1.3153x over previous
//
#include <hip/hip_runtime.h>

#define BATCH   512
#define EMBED   512
#define NF4     (EMBED / 4)       // float4s per row = 128
#define THREADS 512
#define GANCH   4                 // anchors per block -> 128 blocks
#define RPT     4                 // rows per 8-lane group per pass
#define GROUPS  64                // 8 waves * 8 row-groups
#define PASSES  (BATCH / (GROUPS * RPT))   // 2

// Fused: per block, GANCH Gram rows (anchors staged in LDS, stream rows
// register-blocked) + hinge reduction. No workspace. ~60 live VGPR by design
// so the round-1 spill (VGPR=76 vs 128 needed -> scratch) cannot recur.
__global__ __launch_bounds__(THREADS) void fused_loss(
    const float* __restrict__ X,
    const int*   __restrict__ labels,
    const float* __restrict__ mu,
    const float* __restrict__ nv,
    float*       __restrict__ out,
    int n_classes)
{
    __shared__ float4 Alds[GANCH][NF4];    // 8 KB: anchor rows
    __shared__ float  Dl[GANCH][BATCH];    // 8 KB: D[i0+g, :]
    __shared__ float  dijmu[GANCH][BATCH]; // 8 KB: D[i,j]+mu_i for positives
    __shared__ int    lab[BATCH];          // 2 KB
    __shared__ int    nps[GANCH];
    __shared__ float  red[THREADS / 64];

    const int tid   = threadIdx.x;
    const int lane  = tid & 63;
    const int wave  = tid >> 6;
    const int sub   = lane & 7;            // lane within 8-lane row group
    const int rg    = lane >> 3;           // row group within wave
    const int group = (wave << 3) + rg;    // 0..63
    const int i0    = blockIdx.x * GANCH;

    const float4* __restrict__ X4 = (const float4*)X;

    lab[tid] = labels[tid];
    if (tid < GANCH) nps[tid] = 0;
    {   // stage anchors: one float4 per thread, fully coalesced
        const int g = tid >> 7;            // 0..3
        const int f = tid & 127;           // 0..127
        Alds[g][f] = X4[(size_t)(i0 + g) * NF4 + f];
    }
    __syncthreads();

    // ---------------- Phase 1: D[i0..i0+3][:] ----------------
#pragma unroll
    for (int pass = 0; pass < PASSES; ++pass) {
        const int rbase = pass * (GROUPS * RPT) + group * RPT;
        float acc[RPT][GANCH] = {};

#pragma unroll 4
        for (int c = 0; c < 16; ++c) {
            float4 a[GANCH];
#pragma unroll
            for (int g = 0; g < GANCH; ++g)
                a[g] = Alds[g][c * 8 + sub];   // broadcast across row groups
#pragma unroll
            for (int q = 0; q < RPT; ++q) {
                const float4 x = X4[(size_t)(rbase + q) * NF4 + c * 8 + sub];
#pragma unroll
                for (int g = 0; g < GANCH; ++g) {
                    acc[q][g] = fmaf(x.x, a[g].x, acc[q][g]);
                    acc[q][g] = fmaf(x.y, a[g].y, acc[q][g]);
                    acc[q][g] = fmaf(x.z, a[g].z, acc[q][g]);
                    acc[q][g] = fmaf(x.w, a[g].w, acc[q][g]);
                }
            }
        }

        // reduce across the 8 sub-lanes of each row group
#pragma unroll
        for (int off = 1; off <= 4; off <<= 1)
#pragma unroll
            for (int q = 0; q < RPT; ++q)
#pragma unroll
                for (int g = 0; g < GANCH; ++g)
                    acc[q][g] += __shfl_xor(acc[q][g], off, 64);

        if (sub == 0) {
#pragma unroll
            for (int q = 0; q < RPT; ++q)
#pragma unroll
                for (int g = 0; g < GANCH; ++g)
                    Dl[g][rbase + q] = acc[q][g];
        }
    }
    __syncthreads();

    // ---------------- Phase 2: hinge ----------------
    float local = 0.f;

#pragma unroll
    for (int g = 0; g < GANCH; ++g) {
        const int ia = i0 + g;
        const int li = lab[ia];
        if (tid != ia && lab[tid] == li) {
            const int p = atomicAdd(&nps[g], 1);
            dijmu[g][p] = Dl[g][tid] + mu[li];
        }
    }
    __syncthreads();

#pragma unroll
    for (int g = 0; g < GANCH; ++g) {
        const int li = lab[i0 + g];
        if (lab[tid] != li) {              // tid is a valid negative k
            const float dk = Dl[g][tid];
            const int np = nps[g];
            for (int p = 0; p < np; ++p)
                local += fmaxf(dijmu[g][p] - dk, 0.f);
        }
    }

    // margin regularizers folded by block 0
    if (blockIdx.x == 0 && tid < n_classes)
        local -= (mu[tid] + nv[tid]) / (float)n_classes;

    // block reduction -> one atomic per block (128 total)
#pragma unroll
    for (int off = 32; off > 0; off >>= 1)
        local += __shfl_down(local, off, 64);
    if (lane == 0) red[wave] = local;
    __syncthreads();
    if (tid == 0) {
        float s = 0.f;
#pragma unroll
        for (int w = 0; w < THREADS / 64; ++w) s += red[w];
        atomicAdd(out, s);
    }
}

extern "C" void kernel_launch(void* const* d_in, const int* in_sizes, int n_in,
                              void* d_out, int out_size, void* d_ws, size_t ws_size,
                              hipStream_t stream)
{
    const float* X      = (const float*)d_in[0];
    const int*   labels = (const int*)d_in[1];
    const float* mu     = (const float*)d_in[2];
    const float* nv     = (const float*)d_in[3];
    float* out = (float*)d_out;
    const int n_classes = in_sizes[2];

    hipMemsetAsync(d_out, 0, sizeof(float), stream);

    fused_loss<<<dim3(BATCH / GANCH), dim3(THREADS), 0, stream>>>(
        X, labels, mu, nv, out, n_classes);
}